// Round 9
// baseline (158.232 us; speedup 1.0000x reference)
//
#include <hip/hip_runtime.h>
#include <math.h>

#define Bb   256
#define Lq   128
#define D1   768
#define Hh   1024
#define Kk   256
#define K2v  512

// ---- ws float offsets ----
#define OFF_EPSG  0              // 512*256
#define OFF_Z     131072         // 512*256
#define OFF_SCORE 262144         // 512*256
#define OFF_DIST  393216         // 65536
#define OFF_HIST  458752         // 8192 ints
#define OFF_SCAL  466944         // [0]=kl_i [1]=kl_t [2]=align [3]=spare [4]=counter
#define OFF_YSY   466952         // 512
#define OFF_BF    467464         // ushort arena (16B aligned)

// ---- ushort offsets inside bf arena ----
#define UB_XG   0                // 512*768
#define UB_HACT 393216           // 512*1024
#define UB_ZB   917504           // 512*256
#define UB_WT   1048576          // transposed bf16 weights
#define WT_EW1I 0
#define WT_EW1T 786432
#define WT_EW2I 1572864
#define WT_EW2T 2097152
#define WT_SW1I 2621440
#define WT_SW1T 2752512
#define WT_SW2I 2883584
#define WT_SW2T 3014656

typedef __attribute__((ext_vector_type(8))) short short8v;
typedef __attribute__((ext_vector_type(4))) float f32x4;

__device__ __forceinline__ float wred(float v){
#pragma unroll
  for (int m = 32; m; m >>= 1) v += __shfl_xor(v, m, 64);
  return v;
}
__device__ __forceinline__ int wredi(int v){
#pragma unroll
  for (int m = 32; m; m >>= 1) v += __shfl_xor(v, m, 64);
  return v;
}
__device__ __forceinline__ float gelu_exact(float x){
  return 0.5f * x * (1.0f + erff(x * 0.70710678118654752f));
}
__device__ __forceinline__ ushort f2b(float f){
  union { float f; unsigned u; } v; v.f = f;
  return (ushort)((v.u + 0x7FFFu + ((v.u >> 16) & 1u)) >> 16);
}

// ---------------- prep: zero + seq_last + gather/convert + weight transpose ----------------
__global__ __launch_bounds__(256) void k_prep(
    const float* __restrict__ img, const float* __restrict__ txt,
    const float* __restrict__ epsi, const float* __restrict__ epst,
    const int* __restrict__ mask,
    const float* __restrict__ eW1i, const float* __restrict__ eW1t,
    const float* __restrict__ eW2i, const float* __restrict__ eW2t,
    const float* __restrict__ sW1i, const float* __restrict__ sW1t,
    const float* __restrict__ sW2i, const float* __restrict__ sW2t,
    ushort* __restrict__ xgb, float* __restrict__ epsg, ushort* __restrict__ wt,
    int* __restrict__ ghist, float* __restrict__ scal)
{
  __shared__ float lsf[32][33];
  __shared__ int s_last;
  const int bid = blockIdx.x, t = threadIdx.x;
  if (bid < 256){
    if (t < 8) reinterpret_cast<int4*>(ghist)[bid * 8 + t] = make_int4(0,0,0,0);
    if (bid == 0 && t < 8) scal[t] = 0.0f;
    int s = 0;
    if (t < 32){
      int4 v = reinterpret_cast<const int4*>(mask + bid * Lq)[t];
      s = v.x + v.y + v.z + v.w;
    }
    if (t < 64){
      int tot = wredi(s);
      if (t == 0) s_last = tot - 1;
    }
    __syncthreads();
    const int last = s_last;
    if (t < 192){
      float4 v = reinterpret_cast<const float4*>(img + (size_t)(bid*Lq+last)*D1)[t];
      ushort4 o; o.x=f2b(v.x); o.y=f2b(v.y); o.z=f2b(v.z); o.w=f2b(v.w);
      reinterpret_cast<ushort4*>(xgb + (size_t)bid*D1)[t] = o;
      float4 w = reinterpret_cast<const float4*>(txt + (size_t)(bid*Lq+last)*D1)[t];
      ushort4 q; q.x=f2b(w.x); q.y=f2b(w.y); q.z=f2b(w.z); q.w=f2b(w.w);
      reinterpret_cast<ushort4*>(xgb + (size_t)(Bb+bid)*D1)[t] = q;
    }
    if (t < 64){
      reinterpret_cast<float4*>(epsg + (size_t)bid*Kk)[t] =
        reinterpret_cast<const float4*>(epsi + (size_t)(bid*Lq+last)*Kk)[t];
      reinterpret_cast<float4*>(epsg + (size_t)(Bb+bid)*Kk)[t] =
        reinterpret_cast<const float4*>(epst + (size_t)(bid*Lq+last)*Kk)[t];
    }
    return;
  }
  const int wb = bid - 256;
  const float* src; ushort* dst; int Kd, Nd, ti;
  if      (wb < 768){  src=eW1i; dst=wt+WT_EW1I; Kd=768;  Nd=1024; ti=wb; }
  else if (wb < 1536){ src=eW1t; dst=wt+WT_EW1T; Kd=768;  Nd=1024; ti=wb-768; }
  else if (wb < 2048){ src=eW2i; dst=wt+WT_EW2I; Kd=1024; Nd=512;  ti=wb-1536; }
  else if (wb < 2560){ src=eW2t; dst=wt+WT_EW2T; Kd=1024; Nd=512;  ti=wb-2048; }
  else if (wb < 2688){ src=sW1i; dst=wt+WT_SW1I; Kd=256;  Nd=512;  ti=wb-2560; }
  else if (wb < 2816){ src=sW1t; dst=wt+WT_SW1T; Kd=256;  Nd=512;  ti=wb-2688; }
  else if (wb < 2944){ src=sW2i; dst=wt+WT_SW2I; Kd=512;  Nd=256;  ti=wb-2816; }
  else               { src=sW2t; dst=wt+WT_SW2T; Kd=512;  Nd=256;  ti=wb-2944; }
  const int ntile = Nd / 32;
  const int k0 = (ti / ntile) * 32, n0 = (ti % ntile) * 32;
  const int r = t >> 3, q = t & 7;
  float4 v = reinterpret_cast<const float4*>(src + (size_t)(k0+r)*Nd + n0)[q];
  lsf[r][q*4+0]=v.x; lsf[r][q*4+1]=v.y; lsf[r][q*4+2]=v.z; lsf[r][q*4+3]=v.w;
  __syncthreads();
  ushort4 o;
  o.x = f2b(lsf[q*4+0][r]); o.y = f2b(lsf[q*4+1][r]);
  o.z = f2b(lsf[q*4+2][r]); o.w = f2b(lsf[q*4+3][r]);
  *reinterpret_cast<ushort4*>(dst + (size_t)(n0+r)*Kd + k0 + q*4) = o;
}

// ---------------- enc1: G1 (16 rows x 1024 cols, K=768) + bias + LN + gelu -> bf16 ----------------
// 32 blocks x 1024 thr (16 waves). Wave w owns cols [w*64, w*64+64). B-frags direct from WT.
__global__ __launch_bounds__(1024) void k_enc1(
    const ushort* __restrict__ xgb,
    const ushort* __restrict__ WTi, const ushort* __restrict__ WTt,
    const float* __restrict__ b1i, const float* __restrict__ b1t,
    const float* __restrict__ gi,  const float* __restrict__ gt,
    const float* __restrict__ bei, const float* __restrict__ bet,
    ushort* __restrict__ hb)
{
  __shared__ __align__(16) char ALS[16 * 768 * 2];   // A k-major, swizzled
  __shared__ float Hf[16][1028];
  const int tid = threadIdx.x, lane = tid & 63, w = tid >> 6;
  const int r0 = blockIdx.x * 16;
  const ushort* WT = (r0 >= 256) ? WTt : WTi;
  const float* b1 = (r0 >= 256) ? b1t : b1i;
  const float* g  = (r0 >= 256) ? gt  : gi;
  const float* be = (r0 >= 256) ? bet : bei;

  for (int q = tid; q < 16 * 96; q += 1024){
    int m = q / 96, k8 = q % 96;
    short8v v = *reinterpret_cast<const short8v*>(xgb + (size_t)(r0+m)*D1 + k8*8);
    int dq = ((k8 >> 2)*16 + m)*64 + (((k8 & 3) << 4) ^ ((m & 3) << 4));
    *reinterpret_cast<short8v*>(ALS + dq) = v;
  }
  __syncthreads();
  const int l15 = lane & 15, kg = lane >> 4;
  const int cb = w * 64;
  f32x4 acc[4];
#pragma unroll
  for (int c = 0; c < 4; c++) acc[c] = (f32x4){0.f,0.f,0.f,0.f};
#pragma unroll 2
  for (int ks = 0; ks < 24; ks++){
    short8v av = *reinterpret_cast<const short8v*>(
        ALS + (ks*16 + l15)*64 + ((kg*16) ^ ((l15 & 3) << 4)));
#pragma unroll
    for (int c = 0; c < 4; c++){
      short8v bv = *reinterpret_cast<const short8v*>(
          WT + (size_t)(cb + c*16 + l15)*D1 + ks*32 + kg*8);
      acc[c] = __builtin_amdgcn_mfma_f32_16x16x32_bf16(av, bv, acc[c], 0, 0, 0);
    }
  }
#pragma unroll
  for (int c = 0; c < 4; c++){
    const int col = cb + c*16 + l15;
    const float bv = b1[col];
#pragma unroll
    for (int r = 0; r < 4; r++) Hf[kg*4 + r][col] = acc[c][r] + bv;
  }
  __syncthreads();
  // wave w handles row w: LN over 1024
  float s = 0.f, q2 = 0.f;
#pragma unroll
  for (int j = 0; j < 16; j++){
    float x = Hf[w][lane + 64*j];
    s += x; q2 += x*x;
  }
  s = wred(s); q2 = wred(q2);
  const float mean = s * (1.0f/1024.0f);
  const float rstd = rsqrtf(q2 * (1.0f/1024.0f) - mean*mean + 1e-5f);
  const int c0 = lane * 16;
  short8v o0, o1;
#pragma unroll
  for (int j = 0; j < 8; j++){
    float x0 = (Hf[w][c0+j]   - mean)*rstd*g[c0+j]   + be[c0+j];
    float x1 = (Hf[w][c0+8+j] - mean)*rstd*g[c0+8+j] + be[c0+8+j];
    o0[j] = (short)f2b(gelu_exact(x0));
    o1[j] = (short)f2b(gelu_exact(x1));
  }
  *reinterpret_cast<short8v*>(hb + (size_t)(r0+w)*Hh + c0)     = o0;
  *reinterpret_cast<short8v*>(hb + (size_t)(r0+w)*Hh + c0 + 8) = o1;
}

// ---------------- enc2: G2 (16 rows x 512, K=1024) + bias + reparam + normalize + KL ----------------
// 32 blocks x 512 thr (8 waves). Wave w owns cols [w*64, ...).
__global__ __launch_bounds__(512) void k_enc2(
    const ushort* __restrict__ hbA,
    const ushort* __restrict__ WTi, const ushort* __restrict__ WTt,
    const float* __restrict__ b2i, const float* __restrict__ b2t,
    const float* __restrict__ epsg,
    float* __restrict__ z, ushort* __restrict__ zb, float* __restrict__ kl)
{
  __shared__ __align__(16) char ALS[16 * 1024 * 2];
  __shared__ float Hf[16][516];
  const int tid = threadIdx.x, lane = tid & 63, w = tid >> 6;
  const int r0 = blockIdx.x * 16;
  const ushort* WT = (r0 >= 256) ? WTt : WTi;
  const float* b2 = (r0 >= 256) ? b2t : b2i;

  for (int q = tid; q < 16 * 128; q += 512){
    int m = q >> 7, k8 = q & 127;
    short8v v = *reinterpret_cast<const short8v*>(hbA + (size_t)(r0+m)*Hh + k8*8);
    int dq = ((k8 >> 2)*16 + m)*64 + (((k8 & 3) << 4) ^ ((m & 3) << 4));
    *reinterpret_cast<short8v*>(ALS + dq) = v;
  }
  __syncthreads();
  const int l15 = lane & 15, kg = lane >> 4;
  const int cb = w * 64;
  f32x4 acc[4];
#pragma unroll
  for (int c = 0; c < 4; c++) acc[c] = (f32x4){0.f,0.f,0.f,0.f};
#pragma unroll 2
  for (int ks = 0; ks < 32; ks++){
    short8v av = *reinterpret_cast<const short8v*>(
        ALS + (ks*16 + l15)*64 + ((kg*16) ^ ((l15 & 3) << 4)));
#pragma unroll
    for (int c = 0; c < 4; c++){
      short8v bv = *reinterpret_cast<const short8v*>(
          WT + (size_t)(cb + c*16 + l15)*Hh + ks*32 + kg*8);
      acc[c] = __builtin_amdgcn_mfma_f32_16x16x32_bf16(av, bv, acc[c], 0, 0, 0);
    }
  }
#pragma unroll
  for (int c = 0; c < 4; c++){
    const int col = cb + c*16 + l15;
    const float bv = b2[col];
#pragma unroll
    for (int r = 0; r < 4; r++) Hf[kg*4 + r][col] = acc[c][r] + bv;
  }
  __syncthreads();
  // wave w handles rows w and w+8
#pragma unroll
  for (int rr = 0; rr < 2; rr++){
    const int row = w + rr*8;
    const int grow = r0 + row;
    float4 mu = *reinterpret_cast<const float4*>(&Hf[row][lane*4]);
    float4 lv = *reinterpret_cast<const float4*>(&Hf[row][256 + lane*4]);
    float4 ev = reinterpret_cast<const float4*>(epsg + (size_t)grow*Kk)[lane];
    float z0 = mu.x + ev.x * expf(0.5f * lv.x);
    float z1 = mu.y + ev.y * expf(0.5f * lv.y);
    float z2 = mu.z + ev.z * expf(0.5f * lv.z);
    float z3 = mu.w + ev.w * expf(0.5f * lv.w);
    float s2 = wred(z0*z0 + z1*z1 + z2*z2 + z3*z3);
    float klp = (1.0f + lv.x - mu.x*mu.x - expf(lv.x))
              + (1.0f + lv.y - mu.y*mu.y - expf(lv.y))
              + (1.0f + lv.z - mu.z*mu.z - expf(lv.z))
              + (1.0f + lv.w - mu.w*mu.w - expf(lv.w));
    float klt = wred(klp);
    float inv = 1.0f / fmaxf(sqrtf(s2), 1e-12f);
    float4 zv = make_float4(z0*inv, z1*inv, z2*inv, z3*inv);
    reinterpret_cast<float4*>(z)[(size_t)grow * 64 + lane] = zv;
    ushort4 o; o.x=f2b(zv.x); o.y=f2b(zv.y); o.z=f2b(zv.z); o.w=f2b(zv.w);
    reinterpret_cast<ushort4*>(zb)[(size_t)grow * 64 + lane] = o;
    if (lane == 0) atomicAdd(kl + (grow >= 256 ? 1 : 0), -0.5f * klt);
  }
}

// ---------------- sc: full score-MLP per 16-row block (blocks 0..31) + dist/hist (32..159) ----------------
__global__ __launch_bounds__(512) void k_sc(
    const ushort* __restrict__ zb,
    const ushort* __restrict__ W1i, const ushort* __restrict__ W1t,
    const float* __restrict__ sb1i, const float* __restrict__ sb1t,
    const float* __restrict__ sgi,  const float* __restrict__ sgt,
    const float* __restrict__ sbei, const float* __restrict__ sbet,
    const ushort* __restrict__ W2i, const ushort* __restrict__ W2t,
    const float* __restrict__ sb2i, const float* __restrict__ sb2t,
    const float* __restrict__ z, float* __restrict__ score, float* __restrict__ ysy,
    float* __restrict__ dist, int* __restrict__ ghist)
{
  __shared__ __align__(16) char SM[74240];
  const int bid = blockIdx.x, tid = threadIdx.x;
  const int lane = tid & 63, w = tid >> 6;
  if (bid < 32){
    char* ALS = SM;                                             // 8192
    float (*Hf)[516] = reinterpret_cast<float(*)[516]>(SM + 8192);      // 33024
    char* HK = SM + 8192 + 33024;                               // 16384
    float (*SF)[260] = reinterpret_cast<float(*)[260]>(SM + 57600);     // 16640
    const int r0 = bid * 16;
    const ushort* W1 = (r0 >= 256) ? W1t : W1i;
    const float* b1 = (r0 >= 256) ? sb1t : sb1i;
    const float* g  = (r0 >= 256) ? sgt  : sgi;
    const float* be = (r0 >= 256) ? sbet : sbei;
    const ushort* W2 = (r0 >= 256) ? W2t : W2i;
    const float* b2 = (r0 >= 256) ? sb2t : sb2i;

    // stage zb rows
    {
      int q = tid;                   // 512 chunks exactly
      int m = q >> 5, k8 = q & 31;
      short8v v = *reinterpret_cast<const short8v*>(zb + (size_t)(r0+m)*Kk + k8*8);
      int dq = ((k8 >> 2)*16 + m)*64 + (((k8 & 3) << 4) ^ ((m & 3) << 4));
      *reinterpret_cast<short8v*>(ALS + dq) = v;
    }
    __syncthreads();
    const int l15 = lane & 15, kg = lane >> 4;
    // G3: K=256 (8 ksteps), wave w cols [w*64,..)
    {
      const int cb = w * 64;
      f32x4 acc[4];
#pragma unroll
      for (int c = 0; c < 4; c++) acc[c] = (f32x4){0.f,0.f,0.f,0.f};
#pragma unroll
      for (int ks = 0; ks < 8; ks++){
        short8v av = *reinterpret_cast<const short8v*>(
            ALS + (ks*16 + l15)*64 + ((kg*16) ^ ((l15 & 3) << 4)));
#pragma unroll
        for (int c = 0; c < 4; c++){
          short8v bv = *reinterpret_cast<const short8v*>(
              W1 + (size_t)(cb + c*16 + l15)*Kk + ks*32 + kg*8);
          acc[c] = __builtin_amdgcn_mfma_f32_16x16x32_bf16(av, bv, acc[c], 0, 0, 0);
        }
      }
#pragma unroll
      for (int c = 0; c < 4; c++){
        const int col = cb + c*16 + l15;
        const float bv = b1[col];
#pragma unroll
        for (int r = 0; r < 4; r++) Hf[kg*4 + r][col] = acc[c][r] + bv;
      }
    }
    __syncthreads();
    // LN over 512 + gelu -> HK (k-major bf16), wave w rows w, w+8
#pragma unroll
    for (int rr = 0; rr < 2; rr++){
      const int row = w + rr*8;
      float s = 0.f, q2 = 0.f;
#pragma unroll
      for (int j = 0; j < 8; j++){
        float x = Hf[row][lane + 64*j];
        s += x; q2 += x*x;
      }
      s = wred(s); q2 = wred(q2);
      const float mean = s * (1.0f/512.0f);
      const float rstd = rsqrtf(q2 * (1.0f/512.0f) - mean*mean + 1e-5f);
      const int c0 = lane * 8;
      short8v o;
#pragma unroll
      for (int j = 0; j < 8; j++){
        float x = (Hf[row][c0+j] - mean)*rstd*g[c0+j] + be[c0+j];
        o[j] = (short)f2b(gelu_exact(x));
      }
      int dq = ((lane >> 2)*16 + row)*64 + (((lane & 3) << 4) ^ ((row & 3) << 4));
      *reinterpret_cast<short8v*>(HK + dq) = o;
    }
    __syncthreads();
    // G4: K=512 (16 ksteps), wave w cols [w*32, w*32+32)
    {
      const int cw = w * 32;
      f32x4 acc[2];
      acc[0] = (f32x4){0.f,0.f,0.f,0.f}; acc[1] = (f32x4){0.f,0.f,0.f,0.f};
#pragma unroll 2
      for (int ks = 0; ks < 16; ks++){
        short8v av = *reinterpret_cast<const short8v*>(
            HK + (ks*16 + l15)*64 + ((kg*16) ^ ((l15 & 3) << 4)));
#pragma unroll
        for (int c = 0; c < 2; c++){
          short8v bv = *reinterpret_cast<const short8v*>(
              W2 + (size_t)(cw + c*16 + l15)*K2v + ks*32 + kg*8);
          acc[c] = __builtin_amdgcn_mfma_f32_16x16x32_bf16(av, bv, acc[c], 0, 0, 0);
        }
      }
#pragma unroll
      for (int c = 0; c < 2; c++){
        const int col = cw + c*16 + l15;
        const float bv = b2[col];
#pragma unroll
        for (int r = 0; r < 4; r++) SF[kg*4 + r][col] = acc[c][r] + bv;
      }
    }
    __syncthreads();
    // score write + ysy, wave w rows w, w+8
#pragma unroll
    for (int rr = 0; rr < 2; rr++){
      const int row = w + rr*8;
      const int grow = r0 + row;
      float4 sv = *reinterpret_cast<const float4*>(&SF[row][lane*4]);
      reinterpret_cast<float4*>(score)[(size_t)grow * 64 + lane] = sv;
      float4 zv = reinterpret_cast<const float4*>(z)[(size_t)grow * 64 + lane];
      float yp = wred(zv.x*sv.x + zv.y*sv.y + zv.z*sv.z + zv.w*sv.w);
      if (lane == 0) ysy[grow] = yp;
    }
    return;
  }
  // ---- dist/hist role: blocks 32..159, 2 i-rows per block ----
  float (*xsh)[256] = reinterpret_cast<float(*)[256]>(SM);
  int* hl = reinterpret_cast<int*>(SM + 2048);
  const int ti = tid >> 8, tt = tid & 255;
  const int i = (bid - 32) * 2 + ti;
  xsh[ti][tt] = z[(size_t)i * Kk + tt];
  for (int k = tid; k < 8192; k += 512) hl[k] = 0;
  __syncthreads();
  const float4* y4 = reinterpret_cast<const float4*>(z + (size_t)Bb * Kk);
  const float4* x4 = reinterpret_cast<const float4*>(xsh[ti]);
  float acc = 0.0f;
#pragma unroll 4
  for (int d = 0; d < Kk; d += 4){
    float4 xv = x4[d >> 2];
    float4 yv = y4[tt * (Kk/4) + (d >> 2)];
    float d0 = xv.x - yv.x, d1 = xv.y - yv.y, d2 = xv.z - yv.z, d3 = xv.w - yv.w;
    acc += d0*d0 + d1*d1 + d2*d2 + d3*d3;
  }
  dist[i * 256 + tt] = acc;
  int bin = (int)(acc * 2048.0f);
  bin = bin < 0 ? 0 : (bin > 8191 ? 8191 : bin);
  atomicAdd(&hl[bin], 1);
  __syncthreads();
  for (int k = tid; k < 8192; k += 512){
    int c = hl[k];
    if (c) atomicAdd(ghist + k, c);
  }
}

// ---------------- score reduction (+ per-block bw, last-block finalize) ----------------
__global__ __launch_bounds__(256) void k_score(
    const float* __restrict__ z, const float* __restrict__ score,
    const float* __restrict__ dist, const float* __restrict__ ysy,
    const int* __restrict__ ghist, float* __restrict__ scal,
    float* __restrict__ out)
{
  __shared__ __align__(16) float xsh[Kk];
  __shared__ __align__(16) float sxsh[Kk];
  __shared__ int wt4[4];
  __shared__ int bres[2];
  __shared__ float red4[4];
  __shared__ float s_bw2;
  const int i = blockIdx.x, j = threadIdx.x;
  xsh[j]  = z[(size_t)i * Kk + j];
  sxsh[j] = score[(size_t)i * Kk + j];
  {
    const int lane = j & 63, w = j >> 6;
    const int base = j * 32;
    int s = 0;
#pragma unroll
    for (int u = 0; u < 32; u++) s += ghist[base + u];
    int sc = s;
#pragma unroll
    for (int m = 1; m < 64; m <<= 1){
      int o = __shfl_up(sc, m, 64);
      if (lane >= m) sc += o;
    }
    if (lane == 63) wt4[w] = sc;
    __syncthreads();
    int off = 0;
    for (int q = 0; q < w; q++) off += wt4[q];
    int cum = sc + off, basex = cum - s;
#pragma unroll
    for (int rr = 0; rr < 2; rr++){
      int rank = 32768 + rr;
      if (basex < rank && cum >= rank){
        int c = basex;
        for (int u = 0; u < 32; u++){
          c += ghist[base + u];
          if (c >= rank){ bres[rr] = base + u; break; }
        }
      }
    }
    __syncthreads();
    if (j == 0){
      float med = 0.5f * ((bres[0] + 0.5f) + (bres[1] + 0.5f)) * (1.0f / 2048.0f);
      float bw = sqrtf(med * 0.5f);
      bw = fminf(fmaxf(bw, 0.1f), 10.0f);
      s_bw2 = bw * bw;
    }
    __syncthreads();
  }
  const float bw2 = s_bw2;
  const float4* sy4 = reinterpret_cast<const float4*>(score + (size_t)Bb * Kk);
  const float4* x4  = reinterpret_cast<const float4*>(xsh);
  const float4* sx4 = reinterpret_cast<const float4*>(sxsh);
  float ssy = 0, xsy = 0;
#pragma unroll 4
  for (int d = 0; d < Kk; d += 4){
    float4 xv  = x4[d >> 2];
    float4 sxv = sx4[d >> 2];
    float4 syv = sy4[j * (Kk/4) + (d >> 2)];
    ssy += sxv.x*syv.x + sxv.y*syv.y + sxv.z*syv.z + sxv.w*syv.w;
    xsy += xv.x*syv.x + xv.y*syv.y + xv.z*syv.z + xv.w*syv.w;
  }
  float d2 = dist[i * 256 + j];
  float kv = expf(-d2 / (2.0f * bw2));
  float t1 = kv * ssy;
  float t2 = (xsy - ysy[Bb + j]) * kv / bw2;
  float t3 = d2 * kv / (bw2 * bw2) - kv * (float)Kk / bw2;
  float s = wred(t1 + t2 + t3);
  if (!(j & 63)) red4[j >> 6] = s;
  __syncthreads();
  if (j == 0){
    atomicAdd(scal + 2, red4[0] + red4[1] + red4[2] + red4[3]);
    __threadfence();
    int old = atomicAdd(reinterpret_cast<int*>(scal + 4), 1);
    if (old == 255){
      float kli = __int_as_float(atomicAdd(reinterpret_cast<int*>(scal + 0), 0));
      float klt = __int_as_float(atomicAdd(reinterpret_cast<int*>(scal + 1), 0));
      float alg = __int_as_float(atomicAdd(reinterpret_cast<int*>(scal + 2), 0));
      out[0] = 0.5f * (kli + klt) * (1.0f/256.0f) + 0.1f * alg * (1.0f/65536.0f);
    }
  }
}

extern "C" void kernel_launch(void* const* d_in, const int* in_sizes, int n_in,
                              void* d_out, int out_size, void* d_ws, size_t ws_size,
                              hipStream_t stream) {
  (void)in_sizes; (void)n_in; (void)out_size; (void)ws_size;
  const float* img  = (const float*)d_in[0];
  const float* txt  = (const float*)d_in[1];
  const float* epsi = (const float*)d_in[2];
  const float* epst = (const float*)d_in[3];
  const int*   mask = (const int*)d_in[4];
  const float* eW1i = (const float*)d_in[5];
  const float* eb1i = (const float*)d_in[6];
  const float* egi  = (const float*)d_in[7];
  const float* ebei = (const float*)d_in[8];
  const float* eW2i = (const float*)d_in[9];
  const float* eb2i = (const float*)d_in[10];
  const float* eW1t = (const float*)d_in[11];
  const float* eb1t = (const float*)d_in[12];
  const float* egt  = (const float*)d_in[13];
  const float* ebet = (const float*)d_in[14];
  const float* eW2t = (const float*)d_in[15];
  const float* eb2t = (const float*)d_in[16];
  const float* sW1i = (const float*)d_in[17];
  const float* sb1i = (const float*)d_in[18];
  const float* sgi  = (const float*)d_in[19];
  const float* sbei = (const float*)d_in[20];
  const float* sW2i = (const float*)d_in[21];
  const float* sb2i = (const float*)d_in[22];
  const float* sW1t = (const float*)d_in[23];
  const float* sb1t = (const float*)d_in[24];
  const float* sgt  = (const float*)d_in[25];
  const float* sbet = (const float*)d_in[26];
  const float* sW2t = (const float*)d_in[27];
  const float* sb2t = (const float*)d_in[28];

  float*  ws    = (float*)d_ws;
  float*  epsg  = ws + OFF_EPSG;
  float*  z     = ws + OFF_Z;
  float*  score = ws + OFF_SCORE;
  float*  dist  = ws + OFF_DIST;
  int*    ghist = (int*)(ws + OFF_HIST);
  float*  scal  = ws + OFF_SCAL;
  float*  ysy   = ws + OFF_YSY;
  ushort* ub    = (ushort*)(ws + OFF_BF);
  ushort* xgb   = ub + UB_XG;
  ushort* hb    = ub + UB_HACT;
  ushort* zb    = ub + UB_ZB;
  ushort* wt    = ub + UB_WT;

  // 1: prep (zero, seql, gather, weight conv)
  k_prep<<<3328, 256, 0, stream>>>(img, txt, epsi, epst, mask,
                                   eW1i, eW1t, eW2i, eW2t,
                                   sW1i, sW1t, sW2i, sW2t,
                                   xgb, epsg, wt, ghist, scal);
  // 2: enc GEMM1 + LN1 + gelu
  k_enc1<<<32, 1024, 0, stream>>>(xgb, wt+WT_EW1I, wt+WT_EW1T,
                                  eb1i, eb1t, egi, egt, ebei, ebet, hb);
  // 3: enc GEMM2 + reparam + normalize + KL
  k_enc2<<<32, 512, 0, stream>>>(hb, wt+WT_EW2I, wt+WT_EW2T,
                                 eb2i, eb2t, epsg, z, zb, scal);
  // 4: score-MLP (G3+LN2+G4+ysy) || dist/hist
  k_sc<<<160, 512, 0, stream>>>(zb, wt+WT_SW1I, wt+WT_SW1T,
                                sb1i, sb1t, sgi, sgt, sbei, sbet,
                                wt+WT_SW2I, wt+WT_SW2T, sb2i, sb2t,
                                z, score, ysy, dist, ghist);
  // 5: score reduction + bw + finalize
  k_score<<<256, 256, 0, stream>>>(z, score, dist, ysy, ghist, scal, (float*)d_out);
}

// Round 10
// 87.476 us; speedup vs baseline: 1.8089x; 1.8089x over previous
//
#include <hip/hip_runtime.h>
#include <math.h>

#define Bb   256
#define Lq   128
#define D1   768
#define Hh   1024
#define Kk   256
#define K2v  512

// ---- ws float offsets ----
#define OFF_EPSG  0              // 512*256
#define OFF_H1    131072         // 512*1024 f32
#define OFF_H2    655360         // 512*512
#define OFF_H3    917504         // 512*512
#define OFF_Z     1179648        // 512*256
#define OFF_SCORE 1310720        // 512*256
#define OFF_DIST  1441792        // 65536
#define OFF_HIST  1507328        // 8192 ints
#define OFF_SCAL  1515520        // [0]=kl_i [1]=kl_t [2]=align [3]=spare [4]=counter
#define OFF_YSY   1515528        // 512
#define OFF_BF    1516048        // ushort arena (16B aligned)

// ---- ushort offsets inside bf arena ----
#define UB_XG   0                // 512*768
#define UB_WT   393216           // transposed bf16 weights
#define WT_EW1I 0
#define WT_EW1T 786432
#define WT_EW2I 1572864
#define WT_EW2T 2097152
#define WT_SW1I 2621440
#define WT_SW1T 2752512
#define WT_SW2I 2883584
#define WT_SW2T 3014656

typedef __attribute__((ext_vector_type(8))) short short8v;
typedef __attribute__((ext_vector_type(4))) float f32x4;

__device__ __forceinline__ float wred(float v){
#pragma unroll
  for (int m = 32; m; m >>= 1) v += __shfl_xor(v, m, 64);
  return v;
}
__device__ __forceinline__ int wredi(int v){
#pragma unroll
  for (int m = 32; m; m >>= 1) v += __shfl_xor(v, m, 64);
  return v;
}
__device__ __forceinline__ float gelu_exact(float x){
  return 0.5f * x * (1.0f + erff(x * 0.70710678118654752f));
}
__device__ __forceinline__ ushort f2b(float f){
  union { float f; unsigned u; } v; v.f = f;
  return (ushort)((v.u + 0x7FFFu + ((v.u >> 16) & 1u)) >> 16);
}
// staged-LDS byte offset for 8-bf16 chunk k8 of row m (swizzled k-major)
__device__ __forceinline__ int swzq(int k8, int m){
  return ((k8 >> 2)*16 + m)*64 + ((((k8 & 3) << 4)) ^ ((m & 3) << 4));
}
// A-frag read offset for k-step ks (lane l15, kgroup kg)
__device__ __forceinline__ int swzr(int ks, int l15, int kg){
  return (ks*16 + l15)*64 + ((kg*16) ^ ((l15 & 3) << 4));
}

// ---------------- prep: zero + seq_last + gather/convert + weight transpose ----------------
__global__ __launch_bounds__(256) void k_prep(
    const float* __restrict__ img, const float* __restrict__ txt,
    const float* __restrict__ epsi, const float* __restrict__ epst,
    const int* __restrict__ mask,
    const float* __restrict__ eW1i, const float* __restrict__ eW1t,
    const float* __restrict__ eW2i, const float* __restrict__ eW2t,
    const float* __restrict__ sW1i, const float* __restrict__ sW1t,
    const float* __restrict__ sW2i, const float* __restrict__ sW2t,
    ushort* __restrict__ xgb, float* __restrict__ epsg, ushort* __restrict__ wt,
    int* __restrict__ ghist, float* __restrict__ scal, float* __restrict__ ysy)
{
  __shared__ float lsf[32][33];
  __shared__ int s_last;
  const int bid = blockIdx.x, t = threadIdx.x;
  if (bid < 256){
    if (t < 8) reinterpret_cast<int4*>(ghist)[bid * 8 + t] = make_int4(0,0,0,0);
    if (bid == 0 && t < 8) scal[t] = 0.0f;
    if (t < 2) ysy[bid * 2 + t] = 0.0f;
    int s = 0;
    if (t < 32){
      int4 v = reinterpret_cast<const int4*>(mask + bid * Lq)[t];
      s = v.x + v.y + v.z + v.w;
    }
    if (t < 64){
      int tot = wredi(s);
      if (t == 0) s_last = tot - 1;
    }
    __syncthreads();
    const int last = s_last;
    if (t < 192){
      float4 v = reinterpret_cast<const float4*>(img + (size_t)(bid*Lq+last)*D1)[t];
      ushort4 o; o.x=f2b(v.x); o.y=f2b(v.y); o.z=f2b(v.z); o.w=f2b(v.w);
      reinterpret_cast<ushort4*>(xgb + (size_t)bid*D1)[t] = o;
      float4 w = reinterpret_cast<const float4*>(txt + (size_t)(bid*Lq+last)*D1)[t];
      ushort4 q; q.x=f2b(w.x); q.y=f2b(w.y); q.z=f2b(w.z); q.w=f2b(w.w);
      reinterpret_cast<ushort4*>(xgb + (size_t)(Bb+bid)*D1)[t] = q;
    }
    if (t < 64){
      reinterpret_cast<float4*>(epsg + (size_t)bid*Kk)[t] =
        reinterpret_cast<const float4*>(epsi + (size_t)(bid*Lq+last)*Kk)[t];
      reinterpret_cast<float4*>(epsg + (size_t)(Bb+bid)*Kk)[t] =
        reinterpret_cast<const float4*>(epst + (size_t)(bid*Lq+last)*Kk)[t];
    }
    return;
  }
  const int wb = bid - 256;
  const float* src; ushort* dst; int Kd, Nd, ti;
  if      (wb < 768){  src=eW1i; dst=wt+WT_EW1I; Kd=768;  Nd=1024; ti=wb; }
  else if (wb < 1536){ src=eW1t; dst=wt+WT_EW1T; Kd=768;  Nd=1024; ti=wb-768; }
  else if (wb < 2048){ src=eW2i; dst=wt+WT_EW2I; Kd=1024; Nd=512;  ti=wb-1536; }
  else if (wb < 2560){ src=eW2t; dst=wt+WT_EW2T; Kd=1024; Nd=512;  ti=wb-2048; }
  else if (wb < 2688){ src=sW1i; dst=wt+WT_SW1I; Kd=256;  Nd=512;  ti=wb-2560; }
  else if (wb < 2816){ src=sW1t; dst=wt+WT_SW1T; Kd=256;  Nd=512;  ti=wb-2688; }
  else if (wb < 2944){ src=sW2i; dst=wt+WT_SW2I; Kd=512;  Nd=256;  ti=wb-2816; }
  else               { src=sW2t; dst=wt+WT_SW2T; Kd=512;  Nd=256;  ti=wb-2944; }
  const int ntile = Nd / 32;
  const int k0 = (ti / ntile) * 32, n0 = (ti % ntile) * 32;
  const int r = t >> 3, q = t & 7;
  float4 v = reinterpret_cast<const float4*>(src + (size_t)(k0+r)*Nd + n0)[q];
  lsf[r][q*4+0]=v.x; lsf[r][q*4+1]=v.y; lsf[r][q*4+2]=v.z; lsf[r][q*4+3]=v.w;
  __syncthreads();
  ushort4 o;
  o.x = f2b(lsf[q*4+0][r]); o.y = f2b(lsf[q*4+1][r]);
  o.z = f2b(lsf[q*4+2][r]); o.w = f2b(lsf[q*4+3][r]);
  *reinterpret_cast<ushort4*>(dst + (size_t)(n0+r)*Kd + k0 + q*4) = o;
}

// ---------------- enc1: pure GEMM [16 rows x 64 cols], K=768, H1 = xW1 + b1 (f32) ----------------
// grid (16 colblk, 32 rowgrp), 256 thr = 4 waves (1 col-tile each, full K)
__global__ __launch_bounds__(256) void k_enc1(
    const ushort* __restrict__ xgb,
    const ushort* __restrict__ WTi, const ushort* __restrict__ WTt,
    const float* __restrict__ b1i, const float* __restrict__ b1t,
    float* __restrict__ H1)
{
  __shared__ __align__(16) char ALS[16 * 768 * 2];
  const int tid = threadIdx.x, lane = tid & 63, w = tid >> 6;
  const int r0 = blockIdx.y * 16, colbase = blockIdx.x * 64;
  const ushort* WT = (r0 >= 256) ? WTt : WTi;
  const float* b1 = (r0 >= 256) ? b1t : b1i;

  for (int q = tid; q < 16 * 96; q += 256){
    int m = q / 96, k8 = q % 96;
    short8v v = *reinterpret_cast<const short8v*>(xgb + (size_t)(r0+m)*D1 + k8*8);
    *reinterpret_cast<short8v*>(ALS + swzq(k8, m)) = v;
  }
  __syncthreads();
  const int l15 = lane & 15, kg = lane >> 4;
  const int col = colbase + w*16 + l15;
  f32x4 acc = (f32x4){0.f,0.f,0.f,0.f};
#pragma unroll 4
  for (int ks = 0; ks < 24; ks++){
    short8v av = *reinterpret_cast<const short8v*>(ALS + swzr(ks, l15, kg));
    short8v bv = *reinterpret_cast<const short8v*>(WT + (size_t)col*D1 + ks*32 + kg*8);
    acc = __builtin_amdgcn_mfma_f32_16x16x32_bf16(av, bv, acc, 0, 0, 0);
  }
  const float bias = b1[col];
#pragma unroll
  for (int r = 0; r < 4; r++)
    H1[(size_t)(r0 + kg*4 + r) * Hh + col] = acc[r] + bias;
}

// ---------------- enc2: stage[H1 -> LN1 -> gelu -> LDS] + GEMM K=1024 -> H2 = .. + b2 (f32) ----------------
// grid (8 colblk, 32 rowgrp), 512 thr = 8 waves: ct = w&3, khalf = w>>2 (K split in 2)
__global__ __launch_bounds__(512) void k_enc2(
    const float* __restrict__ H1,
    const ushort* __restrict__ WTi, const ushort* __restrict__ WTt,
    const float* __restrict__ gi,  const float* __restrict__ gt,
    const float* __restrict__ bei, const float* __restrict__ bet,
    const float* __restrict__ b2i, const float* __restrict__ b2t,
    float* __restrict__ H2)
{
  __shared__ __align__(16) char ALS[16 * 1024 * 2];
  __shared__ __align__(16) float Rf[4][64][4];
  const int tid = threadIdx.x, lane = tid & 63, w = tid >> 6;
  const int r0 = blockIdx.y * 16, colbase = blockIdx.x * 64;
  const ushort* WT = (r0 >= 256) ? WTt : WTi;
  const float* g  = (r0 >= 256) ? gt  : gi;
  const float* be = (r0 >= 256) ? bet : bei;
  const float* b2 = (r0 >= 256) ? b2t : b2i;

  // LN1 staging: wave w handles rows {w, w+8}; lane covers cols [lane*16, +16)
#pragma unroll
  for (int rr = 0; rr < 2; rr++){
    const int row = w + rr*8, grow = r0 + row;
    const float4* h4 = reinterpret_cast<const float4*>(H1 + (size_t)grow * Hh);
    float4 v0 = h4[lane*4+0], v1 = h4[lane*4+1], v2 = h4[lane*4+2], v3 = h4[lane*4+3];
    float s = v0.x+v0.y+v0.z+v0.w + v1.x+v1.y+v1.z+v1.w
            + v2.x+v2.y+v2.z+v2.w + v3.x+v3.y+v3.z+v3.w;
    float q2 = v0.x*v0.x+v0.y*v0.y+v0.z*v0.z+v0.w*v0.w
             + v1.x*v1.x+v1.y*v1.y+v1.z*v1.z+v1.w*v1.w
             + v2.x*v2.x+v2.y*v2.y+v2.z*v2.z+v2.w*v2.w
             + v3.x*v3.x+v3.y*v3.y+v3.z*v3.z+v3.w*v3.w;
    s = wred(s); q2 = wred(q2);
    const float mean = s * (1.0f/1024.0f);
    const float rstd = rsqrtf(q2 * (1.0f/1024.0f) - mean*mean + 1e-5f);
    const float4* g4  = reinterpret_cast<const float4*>(g);
    const float4* be4 = reinterpret_cast<const float4*>(be);
    float hv[16] = {v0.x,v0.y,v0.z,v0.w, v1.x,v1.y,v1.z,v1.w,
                    v2.x,v2.y,v2.z,v2.w, v3.x,v3.y,v3.z,v3.w};
    short8v o0, o1;
#pragma unroll
    for (int j = 0; j < 16; j++){
      float4 gg = g4[lane*4 + (j>>2)];
      float4 bb = be4[lane*4 + (j>>2)];
      const float gs = (j&3)==0?gg.x:((j&3)==1?gg.y:((j&3)==2?gg.z:gg.w));
      const float bs = (j&3)==0?bb.x:((j&3)==1?bb.y:((j&3)==2?bb.z:bb.w));
      float x = gelu_exact((hv[j] - mean)*rstd*gs + bs);
      if (j < 8) o0[j] = (short)f2b(x); else o1[j-8] = (short)f2b(x);
    }
    *reinterpret_cast<short8v*>(ALS + swzq(lane*2,   row)) = o0;
    *reinterpret_cast<short8v*>(ALS + swzq(lane*2+1, row)) = o1;
  }
  __syncthreads();
  const int l15 = lane & 15, kg = lane >> 4;
  const int ct = w & 3, khalf = w >> 2;
  const int col = colbase + ct*16 + l15;
  f32x4 acc = (f32x4){0.f,0.f,0.f,0.f};
#pragma unroll 4
  for (int i = 0; i < 16; i++){
    const int ks = khalf*16 + i;
    short8v av = *reinterpret_cast<const short8v*>(ALS + swzr(ks, l15, kg));
    short8v bv = *reinterpret_cast<const short8v*>(WT + (size_t)col*Hh + ks*32 + kg*8);
    acc = __builtin_amdgcn_mfma_f32_16x16x32_bf16(av, bv, acc, 0, 0, 0);
  }
  if (khalf) *reinterpret_cast<float4*>(&Rf[ct][lane][0]) = make_float4(acc[0],acc[1],acc[2],acc[3]);
  __syncthreads();
  if (!khalf){
    float4 o = *reinterpret_cast<const float4*>(&Rf[ct][lane][0]);
    const float bias = b2[col];
    float r0v = acc[0]+o.x+bias, r1v = acc[1]+o.y+bias, r2v = acc[2]+o.z+bias, r3v = acc[3]+o.w+bias;
    H2[(size_t)(r0 + kg*4 + 0) * K2v + col] = r0v;
    H2[(size_t)(r0 + kg*4 + 1) * K2v + col] = r1v;
    H2[(size_t)(r0 + kg*4 + 2) * K2v + col] = r2v;
    H2[(size_t)(r0 + kg*4 + 3) * K2v + col] = r3v;
  }
}

// ---------------- sc1: stage[H2 -> reparam -> normalize -> KL -> LDS] + G3 K=256 -> H3 (f32) ----------------
// grid (8 colblk, 32 rowgrp), 256 thr = 4 waves
__global__ __launch_bounds__(256) void k_sc1(
    const float* __restrict__ H2,
    const float* __restrict__ b2i, const float* __restrict__ b2t,
    const float* __restrict__ epsg,
    const ushort* __restrict__ W1i, const ushort* __restrict__ W1t,
    const float* __restrict__ sb1i, const float* __restrict__ sb1t,
    float* __restrict__ z, float* __restrict__ kl, float* __restrict__ H3)
{
  __shared__ __align__(16) char ALS[16 * 256 * 2];
  const int tid = threadIdx.x, lane = tid & 63, w = tid >> 6;
  const int r0 = blockIdx.y * 16, colblk = blockIdx.x, colbase = colblk * 64;
  const float* b2 = (r0 >= 256) ? b2t : b2i;
  const ushort* W1 = (r0 >= 256) ? W1t : W1i;
  const float* sb1 = (r0 >= 256) ? sb1t : sb1i;

#pragma unroll
  for (int rr = 0; rr < 4; rr++){
    const int row = w + rr*4, grow = r0 + row;
    const float4* h4 = reinterpret_cast<const float4*>(H2 + (size_t)grow * K2v);
    float4 mu = h4[lane], lv = h4[64 + lane];
    float4 bm = reinterpret_cast<const float4*>(b2)[lane];
    float4 bl = reinterpret_cast<const float4*>(b2)[64 + lane];
    mu.x += bm.x; mu.y += bm.y; mu.z += bm.z; mu.w += bm.w;
    lv.x += bl.x; lv.y += bl.y; lv.z += bl.z; lv.w += bl.w;
    float4 ev = reinterpret_cast<const float4*>(epsg)[(size_t)grow * 64 + lane];
    float z0 = mu.x + ev.x * expf(0.5f * lv.x);
    float z1 = mu.y + ev.y * expf(0.5f * lv.y);
    float z2 = mu.z + ev.z * expf(0.5f * lv.z);
    float z3 = mu.w + ev.w * expf(0.5f * lv.w);
    float s2 = wred(z0*z0 + z1*z1 + z2*z2 + z3*z3);
    float klp = (1.0f + lv.x - mu.x*mu.x - expf(lv.x))
              + (1.0f + lv.y - mu.y*mu.y - expf(lv.y))
              + (1.0f + lv.z - mu.z*mu.z - expf(lv.z))
              + (1.0f + lv.w - mu.w*mu.w - expf(lv.w));
    float klt = wred(klp);
    float inv = 1.0f / fmaxf(sqrtf(s2), 1e-12f);
    float4 zv = make_float4(z0*inv, z1*inv, z2*inv, z3*inv);
    if (colblk == 0){
      reinterpret_cast<float4*>(z)[(size_t)grow * 64 + lane] = zv;
      if (lane == 0) atomicAdd(kl + (grow >= 256 ? 1 : 0), -0.5f * klt);
    }
    ushort4 o; o.x=f2b(zv.x); o.y=f2b(zv.y); o.z=f2b(zv.z); o.w=f2b(zv.w);
    *reinterpret_cast<ushort4*>(ALS + swzq(lane >> 1, row) + (lane & 1)*8) = o;
  }
  __syncthreads();
  const int l15 = lane & 15, kg = lane >> 4;
  const int col = colbase + w*16 + l15;
  f32x4 acc = (f32x4){0.f,0.f,0.f,0.f};
#pragma unroll
  for (int ks = 0; ks < 8; ks++){
    short8v av = *reinterpret_cast<const short8v*>(ALS + swzr(ks, l15, kg));
    short8v bv = *reinterpret_cast<const short8v*>(W1 + (size_t)col*Kk + ks*32 + kg*8);
    acc = __builtin_amdgcn_mfma_f32_16x16x32_bf16(av, bv, acc, 0, 0, 0);
  }
  const float bias = sb1[col];
#pragma unroll
  for (int r = 0; r < 4; r++)
    H3[(size_t)(r0 + kg*4 + r) * K2v + col] = acc[r] + bias;
}

// ---------------- sc2: blocks 0..127: stage[H3->LN2->gelu] + G4 K=512 + score + ysy;
//                  blocks 128..383: dist/hist ----------------
__global__ __launch_bounds__(256) void k_sc2(
    const float* __restrict__ H3,
    const float* __restrict__ sgi,  const float* __restrict__ sgt,
    const float* __restrict__ sbei, const float* __restrict__ sbet,
    const ushort* __restrict__ W2i, const ushort* __restrict__ W2t,
    const float* __restrict__ sb2i, const float* __restrict__ sb2t,
    const float* __restrict__ z, float* __restrict__ score, float* __restrict__ ysy,
    float* __restrict__ dist, int* __restrict__ ghist)
{
  __shared__ __align__(16) char SM[33792];
  const int bid = blockIdx.x, tid = threadIdx.x;
  if (bid < 128){
    char* ALS = SM;                       // 16*512*2 = 16384
    const int lane = tid & 63, w = tid >> 6;
    const int r0 = (bid >> 2) * 16, colbase = (bid & 3) * 64;
    const float* g  = (r0 >= 256) ? sgt  : sgi;
    const float* be = (r0 >= 256) ? sbet : sbei;
    const ushort* W2 = (r0 >= 256) ? W2t : W2i;
    const float* b2 = (r0 >= 256) ? sb2t : sb2i;
#pragma unroll
    for (int rr = 0; rr < 4; rr++){
      const int row = w + rr*4, grow = r0 + row;
      const float4* h4 = reinterpret_cast<const float4*>(H3 + (size_t)grow * K2v);
      float4 a = h4[lane*2], b = h4[lane*2+1];
      float s = a.x+a.y+a.z+a.w + b.x+b.y+b.z+b.w;
      float q2 = a.x*a.x+a.y*a.y+a.z*a.z+a.w*a.w + b.x*b.x+b.y*b.y+b.z*b.z+b.w*b.w;
      s = wred(s); q2 = wred(q2);
      const float mean = s * (1.0f/512.0f);
      const float rstd = rsqrtf(q2 * (1.0f/512.0f) - mean*mean + 1e-5f);
      float4 g0 = reinterpret_cast<const float4*>(g)[lane*2];
      float4 g1 = reinterpret_cast<const float4*>(g)[lane*2+1];
      float4 e0 = reinterpret_cast<const float4*>(be)[lane*2];
      float4 e1 = reinterpret_cast<const float4*>(be)[lane*2+1];
      short8v o;
      o[0] = (short)f2b(gelu_exact((a.x-mean)*rstd*g0.x + e0.x));
      o[1] = (short)f2b(gelu_exact((a.y-mean)*rstd*g0.y + e0.y));
      o[2] = (short)f2b(gelu_exact((a.z-mean)*rstd*g0.z + e0.z));
      o[3] = (short)f2b(gelu_exact((a.w-mean)*rstd*g0.w + e0.w));
      o[4] = (short)f2b(gelu_exact((b.x-mean)*rstd*g1.x + e1.x));
      o[5] = (short)f2b(gelu_exact((b.y-mean)*rstd*g1.y + e1.y));
      o[6] = (short)f2b(gelu_exact((b.z-mean)*rstd*g1.z + e1.z));
      o[7] = (short)f2b(gelu_exact((b.w-mean)*rstd*g1.w + e1.w));
      *reinterpret_cast<short8v*>(ALS + swzq(lane, row)) = o;
    }
    __syncthreads();
    const int l15 = lane & 15, kg = lane >> 4;
    const int col = colbase + w*16 + l15;
    f32x4 acc = (f32x4){0.f,0.f,0.f,0.f};
#pragma unroll 4
    for (int ks = 0; ks < 16; ks++){
      short8v av = *reinterpret_cast<const short8v*>(ALS + swzr(ks, l15, kg));
      short8v bv = *reinterpret_cast<const short8v*>(W2 + (size_t)col*K2v + ks*32 + kg*8);
      acc = __builtin_amdgcn_mfma_f32_16x16x32_bf16(av, bv, acc, 0, 0, 0);
    }
    const float bias = b2[col];
    float part[4];
#pragma unroll
    for (int r = 0; r < 4; r++){
      const int grow = r0 + kg*4 + r;
      const float sv = acc[r] + bias;
      score[(size_t)grow * Kk + col] = sv;
      part[r] = z[(size_t)grow * Kk + col] * sv;
    }
#pragma unroll
    for (int m = 1; m < 16; m <<= 1){
#pragma unroll
      for (int r = 0; r < 4; r++) part[r] += __shfl_xor(part[r], m, 64);
    }
    if (l15 == 0){
#pragma unroll
      for (int r = 0; r < 4; r++) atomicAdd(&ysy[r0 + kg*4 + r], part[r]);
    }
    return;
  }
  // dist role
  float* xsh = reinterpret_cast<float*>(SM);          // 1024 B
  int* hl = reinterpret_cast<int*>(SM + 1024);        // 32768 B
  const int i = bid - 128, j = tid;
  xsh[j] = z[(size_t)i * Kk + j];
  for (int k = j; k < 8192; k += 256) hl[k] = 0;
  __syncthreads();
  const float4* y4 = reinterpret_cast<const float4*>(z + (size_t)Bb * Kk);
  const float4* x4 = reinterpret_cast<const float4*>(xsh);
  float acc = 0.0f;
#pragma unroll 4
  for (int d = 0; d < Kk; d += 4){
    float4 xv = x4[d >> 2];
    float4 yv = y4[j * (Kk/4) + (d >> 2)];
    float d0 = xv.x - yv.x, d1 = xv.y - yv.y, d2 = xv.z - yv.z, d3 = xv.w - yv.w;
    acc += d0*d0 + d1*d1 + d2*d2 + d3*d3;
  }
  dist[i * 256 + j] = acc;
  int bin = (int)(acc * 2048.0f);
  bin = bin < 0 ? 0 : (bin > 8191 ? 8191 : bin);
  atomicAdd(&hl[bin], 1);
  __syncthreads();
  for (int k = j; k < 8192; k += 256){
    int c = hl[k];
    if (c) atomicAdd(ghist + k, c);
  }
}

// ---------------- score reduction (+ per-block bw, last-block finalize) ----------------
__global__ __launch_bounds__(256) void k_score(
    const float* __restrict__ z, const float* __restrict__ score,
    const float* __restrict__ dist, const float* __restrict__ ysy,
    const int* __restrict__ ghist, float* __restrict__ scal,
    float* __restrict__ out)
{
  __shared__ __align__(16) float xsh[Kk];
  __shared__ __align__(16) float sxsh[Kk];
  __shared__ int wt4[4];
  __shared__ int bres[2];
  __shared__ float red4[4];
  __shared__ float s_bw2;
  const int i = blockIdx.x, j = threadIdx.x;
  xsh[j]  = z[(size_t)i * Kk + j];
  sxsh[j] = score[(size_t)i * Kk + j];
  {
    const int lane = j & 63, w = j >> 6;
    const int base = j * 32;
    int s = 0;
#pragma unroll
    for (int u = 0; u < 32; u++) s += ghist[base + u];
    int sc = s;
#pragma unroll
    for (int m = 1; m < 64; m <<= 1){
      int o = __shfl_up(sc, m, 64);
      if (lane >= m) sc += o;
    }
    if (lane == 63) wt4[w] = sc;
    __syncthreads();
    int off = 0;
    for (int q = 0; q < w; q++) off += wt4[q];
    int cum = sc + off, basex = cum - s;
#pragma unroll
    for (int rr = 0; rr < 2; rr++){
      int rank = 32768 + rr;
      if (basex < rank && cum >= rank){
        int c = basex;
        for (int u = 0; u < 32; u++){
          c += ghist[base + u];
          if (c >= rank){ bres[rr] = base + u; break; }
        }
      }
    }
    __syncthreads();
    if (j == 0){
      float med = 0.5f * ((bres[0] + 0.5f) + (bres[1] + 0.5f)) * (1.0f / 2048.0f);
      float bw = sqrtf(med * 0.5f);
      bw = fminf(fmaxf(bw, 0.1f), 10.0f);
      s_bw2 = bw * bw;
    }
    __syncthreads();
  }
  const float bw2 = s_bw2;
  const float4* sy4 = reinterpret_cast<const float4*>(score + (size_t)Bb * Kk);
  const float4* x4  = reinterpret_cast<const float4*>(xsh);
  const float4* sx4 = reinterpret_cast<const float4*>(sxsh);
  float ssy = 0, xsy = 0;
#pragma unroll 4
  for (int d = 0; d < Kk; d += 4){
    float4 xv  = x4[d >> 2];
    float4 sxv = sx4[d >> 2];
    float4 syv = sy4[j * (Kk/4) + (d >> 2)];
    ssy += sxv.x*syv.x + sxv.y*syv.y + sxv.z*syv.z + sxv.w*syv.w;
    xsy += xv.x*syv.x + xv.y*syv.y + xv.z*syv.z + xv.w*syv.w;
  }
  float d2 = dist[i * 256 + j];
  float kv = expf(-d2 / (2.0f * bw2));
  float t1 = kv * ssy;
  float t2 = (xsy - ysy[Bb + j]) * kv / bw2;
  float t3 = d2 * kv / (bw2 * bw2) - kv * (float)Kk / bw2;
  float s = wred(t1 + t2 + t3);
  if (!(j & 63)) red4[j >> 6] = s;
  __syncthreads();
  if (j == 0){
    atomicAdd(scal + 2, red4[0] + red4[1] + red4[2] + red4[3]);
    __threadfence();
    int old = atomicAdd(reinterpret_cast<int*>(scal + 4), 1);
    if (old == 255){
      float kli = __int_as_float(atomicAdd(reinterpret_cast<int*>(scal + 0), 0));
      float klt = __int_as_float(atomicAdd(reinterpret_cast<int*>(scal + 1), 0));
      float alg = __int_as_float(atomicAdd(reinterpret_cast<int*>(scal + 2), 0));
      out[0] = 0.5f * (kli + klt) * (1.0f/256.0f) + 0.1f * alg * (1.0f/65536.0f);
    }
  }
}

extern "C" void kernel_launch(void* const* d_in, const int* in_sizes, int n_in,
                              void* d_out, int out_size, void* d_ws, size_t ws_size,
                              hipStream_t stream) {
  (void)in_sizes; (void)n_in; (void)out_size; (void)ws_size;
  const float* img  = (const float*)d_in[0];
  const float* txt  = (const float*)d_in[1];
  const float* epsi = (const float*)d_in[2];
  const float* epst = (const float*)d_in[3];
  const int*   mask = (const int*)d_in[4];
  const float* eW1i = (const float*)d_in[5];
  const float* eb1i = (const float*)d_in[6];
  const float* egi  = (const float*)d_in[7];
  const float* ebei = (const float*)d_in[8];
  const float* eW2i = (const float*)d_in[9];
  const float* eb2i = (const float*)d_in[10];
  const float* eW1t = (const float*)d_in[11];
  const float* eb1t = (const float*)d_in[12];
  const float* egt  = (const float*)d_in[13];
  const float* ebet = (const float*)d_in[14];
  const float* eW2t = (const float*)d_in[15];
  const float* eb2t = (const float*)d_in[16];
  const float* sW1i = (const float*)d_in[17];
  const float* sb1i = (const float*)d_in[18];
  const float* sgi  = (const float*)d_in[19];
  const float* sbei = (const float*)d_in[20];
  const float* sW2i = (const float*)d_in[21];
  const float* sb2i = (const float*)d_in[22];
  const float* sW1t = (const float*)d_in[23];
  const float* sb1t = (const float*)d_in[24];
  const float* sgt  = (const float*)d_in[25];
  const float* sbet = (const float*)d_in[26];
  const float* sW2t = (const float*)d_in[27];
  const float* sb2t = (const float*)d_in[28];

  float*  ws    = (float*)d_ws;
  float*  epsg  = ws + OFF_EPSG;
  float*  H1    = ws + OFF_H1;
  float*  H2    = ws + OFF_H2;
  float*  H3    = ws + OFF_H3;
  float*  z     = ws + OFF_Z;
  float*  score = ws + OFF_SCORE;
  float*  dist  = ws + OFF_DIST;
  int*    ghist = (int*)(ws + OFF_HIST);
  float*  scal  = ws + OFF_SCAL;
  float*  ysy   = ws + OFF_YSY;
  ushort* ub    = (ushort*)(ws + OFF_BF);
  ushort* xgb   = ub + UB_XG;
  ushort* wt    = ub + UB_WT;

  // 1: prep
  k_prep<<<3328, 256, 0, stream>>>(img, txt, epsi, epst, mask,
                                   eW1i, eW1t, eW2i, eW2t,
                                   sW1i, sW1t, sW2i, sW2t,
                                   xgb, epsg, wt, ghist, scal, ysy);
  // 2: enc GEMM1 -> H1 (f32, with bias)
  k_enc1<<<dim3(16, 32), 256, 0, stream>>>(xgb, wt+WT_EW1I, wt+WT_EW1T, eb1i, eb1t, H1);
  // 3: [LN1+gelu inline] + enc GEMM2 -> H2 (f32, with bias)
  k_enc2<<<dim3(8, 32), 512, 0, stream>>>(H1, wt+WT_EW2I, wt+WT_EW2T,
                                          egi, egt, ebei, ebet, eb2i, eb2t, H2);
  // 4: [reparam+normalize+KL inline] + sc GEMM1 -> H3 (f32, with bias); writes z
  k_sc1<<<dim3(8, 32), 256, 0, stream>>>(H2, eb2i, eb2t, epsg,
                                         wt+WT_SW1I, wt+WT_SW1T, sb1i, sb1t,
                                         z, scal, H3);
  // 5: [LN2+gelu inline] + sc GEMM2 + score/ysy  ||  dist/hist
  k_sc2<<<384, 256, 0, stream>>>(H3, sgi, sgt, sbei, sbet,
                                 wt+WT_SW2I, wt+WT_SW2T, sb2i, sb2t,
                                 z, score, ysy, dist, ghist);
  // 6: score reduction + bw + finalize
  k_score<<<256, 256, 0, stream>>>(z, score, dist, ysy, ghist, scal, (float*)d_out);
}